// Round 1
// baseline (779.011 us; speedup 1.0000x reference)
//
#include <hip/hip_runtime.h>

#define T_TOKENS 2048
#define DIM 1024
#define ISZ 2048
#define NEXP 8
#define NPAIRS (T_TOKENS * 2)
#define CAP (NPAIRS + 64)

typedef __attribute__((ext_vector_type(8))) short bf16x8;
typedef __attribute__((ext_vector_type(4))) float f32x4;

// ---------------- ws layout ----------------
// counts[8] @0, cursor[8] @32, offsets[8] @64, pad to 128
// topk_idx int[4096], topk_w float[4096], row_token int[CAP], row_w float[CAP]
// xg bf16[CAP][DIM], h bf16[CAP][ISZ]
constexpr size_t OFF_COUNTS = 0;
constexpr size_t OFF_CURSOR = 32;
constexpr size_t OFF_OFFSETS = 64;
constexpr size_t OFF_TOPK_I = 128;
constexpr size_t OFF_TOPK_W = OFF_TOPK_I + (size_t)NPAIRS * 4;
constexpr size_t OFF_ROW_T  = OFF_TOPK_W + (size_t)NPAIRS * 4;
constexpr size_t OFF_ROW_W  = OFF_ROW_T + (size_t)CAP * 4;
constexpr size_t OFF_XG     = (OFF_ROW_W + (size_t)CAP * 4 + 255) & ~(size_t)255;
constexpr size_t OFF_H      = OFF_XG + (size_t)CAP * DIM * 2;

__device__ __forceinline__ ushort f2bf(float f) {
    union { float f; unsigned u; } v; v.f = f;
    unsigned u = v.u;
    u += 0x7FFFu + ((u >> 16) & 1u);   // RNE
    return (ushort)(u >> 16);
}

__device__ __forceinline__ void cvt8_store(ushort* dst, float4 a, float4 b) {
    ushort4 c0; c0.x = f2bf(a.x); c0.y = f2bf(a.y); c0.z = f2bf(a.z); c0.w = f2bf(a.w);
    ushort4 c1; c1.x = f2bf(b.x); c1.y = f2bf(b.y); c1.z = f2bf(b.z); c1.w = f2bf(b.w);
    *(ushort4*)dst = c0;
    *(ushort4*)(dst + 4) = c1;
}

// ---------------- router: one wave per token ----------------
__global__ void router_kernel(const float* __restrict__ x,
                              const float* __restrict__ gw,
                              float* __restrict__ logits_out,
                              int* __restrict__ topk_idx,
                              float* __restrict__ topk_w,
                              int* __restrict__ counts) {
    int gwave = (int)((blockIdx.x * blockDim.x + threadIdx.x) >> 6);
    int lane = threadIdx.x & 63;
    if (gwave >= T_TOKENS) return;
    const float* xr = x + (size_t)gwave * DIM;
    float xv[16];
#pragma unroll
    for (int i = 0; i < 16; i++) xv[i] = xr[i * 64 + lane];
    float lg[8];
#pragma unroll
    for (int e = 0; e < 8; e++) {
        const float* g = gw + e * DIM;
        float s = 0.f;
#pragma unroll
        for (int i = 0; i < 16; i++) s += xv[i] * g[i * 64 + lane];
#pragma unroll
        for (int off = 32; off > 0; off >>= 1) s += __shfl_xor(s, off, 64);
        lg[e] = s;
    }
    if (lane == 0) {
#pragma unroll
        for (int e = 0; e < 8; e++) logits_out[gwave * 8 + e] = lg[e];
        int e0 = 0; float l0 = lg[0];
#pragma unroll
        for (int e = 1; e < 8; e++) if (lg[e] > l0) { l0 = lg[e]; e0 = e; }
        int e1 = -1; float l1 = -1e30f;
#pragma unroll
        for (int e = 0; e < 8; e++) if (e != e0 && lg[e] > l1) { l1 = lg[e]; e1 = e; }
        float w0 = 1.f / (1.f + __expf(l1 - l0));   // = s0/(s0+s1)
        float w1 = 1.f - w0;
        topk_idx[gwave * 2] = e0; topk_idx[gwave * 2 + 1] = e1;
        topk_w[gwave * 2] = w0;  topk_w[gwave * 2 + 1] = w1;
        atomicAdd(&counts[e0], 1);
        atomicAdd(&counts[e1], 1);
    }
}

__global__ void scan_kernel(const int* __restrict__ counts, int* __restrict__ offsets) {
    if (threadIdx.x == 0) {
        int o = 0;
        for (int e = 0; e < NEXP; e++) { offsets[e] = o; o += counts[e]; }
    }
}

__global__ void assign_kernel(const int* __restrict__ topk_idx,
                              const float* __restrict__ topk_w,
                              const int* __restrict__ offsets,
                              int* __restrict__ cursor,
                              int* __restrict__ row_token,
                              float* __restrict__ row_w) {
    int t = blockIdx.x * blockDim.x + threadIdx.x;
    if (t >= T_TOKENS) return;
    for (int k = 0; k < 2; k++) {
        int e = topk_idx[t * 2 + k];
        int pos = atomicAdd(&cursor[e], 1);
        int slot = offsets[e] + pos;
        row_token[slot] = t;
        row_w[slot] = topk_w[t * 2 + k];
    }
}

// gather one token row -> bf16, one block per pair
__global__ void gather_kernel(const float* __restrict__ x,
                              const int* __restrict__ row_token,
                              ushort* __restrict__ xg) {
    int slot = blockIdx.x;
    int t = row_token[slot];
    const float4* src = (const float4*)(x + (size_t)t * DIM);
    ushort* dst = xg + (size_t)slot * DIM;
    int i = threadIdx.x;               // 256 threads * 4 floats = 1024
    float4 v = src[i];
    ushort4 o; o.x = f2bf(v.x); o.y = f2bf(v.y); o.z = f2bf(v.z); o.w = f2bf(v.w);
    *(ushort4*)(dst + i * 4) = o;
}

// ---------------- GEMM 1: g/u + SwiGLU -> h (bf16) ----------------
// tile 64(M) x 64(N), BK=32; 4 waves in 2x2; per wave 2x2 mfma tiles
__global__ __launch_bounds__(256) void gemm_gu_kernel(
    const ushort* __restrict__ xg,
    const float* __restrict__ w_gate,
    const float* __restrict__ w_up,
    const int* __restrict__ offsets, const int* __restrict__ counts,
    ushort* __restrict__ h) {
    int e = blockIdx.z;
    int cnt = counts[e];
    int rt = blockIdx.x * 64;
    if (rt >= cnt) return;
    int row0 = offsets[e] + rt;
    int rows_valid = cnt - rt; if (rows_valid > 64) rows_valid = 64;
    int col0 = blockIdx.y * 64;

    __shared__ ushort sA[64 * 32];
    __shared__ ushort sG[64 * 32];
    __shared__ ushort sU[64 * 32];

    int tid = threadIdx.x;
    int wave = tid >> 6, lane = tid & 63;
    int wr = wave >> 1, wc = wave & 1;
    int lm = lane & 15, lq = lane >> 4;
    int srow = tid >> 2, scg = tid & 3;    // 64 rows x 4 groups of 8

    f32x4 accG[2][2] = {};
    f32x4 accU[2][2] = {};

    const float* wg_base = w_gate + (size_t)e * ISZ * DIM;
    const float* wu_base = w_up   + (size_t)e * ISZ * DIM;

    for (int k0 = 0; k0 < DIM; k0 += 32) {
        // A: bf16 gathered rows
        uint4 av = *(const uint4*)(xg + (size_t)(row0 + srow) * DIM + k0 + scg * 8);
        *(uint4*)(sA + srow * 32 + scg * 8) = av;
        // B gate / up: fp32 -> bf16
        {
            const float* wp = wg_base + (size_t)(col0 + srow) * DIM + k0 + scg * 8;
            float4 b0 = *(const float4*)wp;
            float4 b1 = *(const float4*)(wp + 4);
            cvt8_store(sG + srow * 32 + scg * 8, b0, b1);
        }
        {
            const float* wp = wu_base + (size_t)(col0 + srow) * DIM + k0 + scg * 8;
            float4 b0 = *(const float4*)wp;
            float4 b1 = *(const float4*)(wp + 4);
            cvt8_store(sU + srow * 32 + scg * 8, b0, b1);
        }
        __syncthreads();

        bf16x8 a[2], bg[2], bu[2];
#pragma unroll
        for (int i = 0; i < 2; i++)
            a[i] = *(const bf16x8*)(sA + (wr * 32 + i * 16 + lm) * 32 + lq * 8);
#pragma unroll
        for (int j = 0; j < 2; j++) {
            bg[j] = *(const bf16x8*)(sG + (wc * 32 + j * 16 + lm) * 32 + lq * 8);
            bu[j] = *(const bf16x8*)(sU + (wc * 32 + j * 16 + lm) * 32 + lq * 8);
        }
#pragma unroll
        for (int i = 0; i < 2; i++)
#pragma unroll
            for (int j = 0; j < 2; j++) {
                accG[i][j] = __builtin_amdgcn_mfma_f32_16x16x32_bf16(a[i], bg[j], accG[i][j], 0, 0, 0);
                accU[i][j] = __builtin_amdgcn_mfma_f32_16x16x32_bf16(a[i], bu[j], accU[i][j], 0, 0, 0);
            }
        __syncthreads();
    }

    // epilogue: h = silu(g) * u, bf16
#pragma unroll
    for (int i = 0; i < 2; i++)
#pragma unroll
        for (int r = 0; r < 4; r++) {
            int lrow = wr * 32 + i * 16 + lq * 4 + r;
            if (lrow < rows_valid) {
#pragma unroll
                for (int j = 0; j < 2; j++) {
                    float g = accG[i][j][r], u = accU[i][j][r];
                    float hv = g / (1.f + __expf(-g)) * u;
                    int col = col0 + wc * 32 + j * 16 + lm;
                    h[(size_t)(row0 + lrow) * ISZ + col] = f2bf(hv);
                }
            }
        }
}

// ---------------- GEMM 2: h x w_down^T -> scaled atomic add into out ----------------
__global__ __launch_bounds__(256) void gemm_down_kernel(
    const ushort* __restrict__ h,
    const float* __restrict__ w_down,
    const int* __restrict__ offsets, const int* __restrict__ counts,
    const int* __restrict__ row_token, const float* __restrict__ row_w,
    float* __restrict__ out) {
    int e = blockIdx.z;
    int cnt = counts[e];
    int rt = blockIdx.x * 64;
    if (rt >= cnt) return;
    int row0 = offsets[e] + rt;
    int rows_valid = cnt - rt; if (rows_valid > 64) rows_valid = 64;
    int col0 = blockIdx.y * 64;   // d dim

    __shared__ ushort sA[64 * 32];
    __shared__ ushort sB[64 * 32];

    int tid = threadIdx.x;
    int wave = tid >> 6, lane = tid & 63;
    int wr = wave >> 1, wc = wave & 1;
    int lm = lane & 15, lq = lane >> 4;
    int srow = tid >> 2, scg = tid & 3;

    f32x4 acc[2][2] = {};
    const float* wb = w_down + (size_t)e * DIM * ISZ;

    for (int k0 = 0; k0 < ISZ; k0 += 32) {
        uint4 av = *(const uint4*)(h + (size_t)(row0 + srow) * ISZ + k0 + scg * 8);
        *(uint4*)(sA + srow * 32 + scg * 8) = av;
        const float* wp = wb + (size_t)(col0 + srow) * ISZ + k0 + scg * 8;
        float4 b0 = *(const float4*)wp;
        float4 b1 = *(const float4*)(wp + 4);
        cvt8_store(sB + srow * 32 + scg * 8, b0, b1);
        __syncthreads();

        bf16x8 a[2], b[2];
#pragma unroll
        for (int i = 0; i < 2; i++)
            a[i] = *(const bf16x8*)(sA + (wr * 32 + i * 16 + lm) * 32 + lq * 8);
#pragma unroll
        for (int j = 0; j < 2; j++)
            b[j] = *(const bf16x8*)(sB + (wc * 32 + j * 16 + lm) * 32 + lq * 8);
#pragma unroll
        for (int i = 0; i < 2; i++)
#pragma unroll
            for (int j = 0; j < 2; j++)
                acc[i][j] = __builtin_amdgcn_mfma_f32_16x16x32_bf16(a[i], b[j], acc[i][j], 0, 0, 0);
        __syncthreads();
    }

#pragma unroll
    for (int i = 0; i < 2; i++)
#pragma unroll
        for (int r = 0; r < 4; r++) {
            int lrow = wr * 32 + i * 16 + lq * 4 + r;
            if (lrow < rows_valid) {
                int slot = row0 + lrow;
                float sc = row_w[slot];
                int t = row_token[slot];
#pragma unroll
                for (int j = 0; j < 2; j++) {
                    int col = col0 + wc * 32 + j * 16 + lm;
                    atomicAdd(out + (size_t)t * DIM + col, acc[i][j][r] * sc);
                }
            }
        }
}

extern "C" void kernel_launch(void* const* d_in, const int* in_sizes, int n_in,
                              void* d_out, int out_size, void* d_ws, size_t ws_size,
                              hipStream_t stream) {
    const float* x      = (const float*)d_in[0];
    const float* gate_w = (const float*)d_in[1];
    const float* w_gate = (const float*)d_in[2];
    const float* w_up   = (const float*)d_in[3];
    const float* w_down = (const float*)d_in[4];

    float* out = (float*)d_out;
    float* logits_out = out + (size_t)T_TOKENS * DIM;

    char* ws = (char*)d_ws;
    int*    counts    = (int*)(ws + OFF_COUNTS);
    int*    cursor    = (int*)(ws + OFF_CURSOR);
    int*    offsets   = (int*)(ws + OFF_OFFSETS);
    int*    topk_idx  = (int*)(ws + OFF_TOPK_I);
    float*  topk_w    = (float*)(ws + OFF_TOPK_W);
    int*    row_token = (int*)(ws + OFF_ROW_T);
    float*  row_w     = (float*)(ws + OFF_ROW_W);
    ushort* xg        = (ushort*)(ws + OFF_XG);
    ushort* h         = (ushort*)(ws + OFF_H);

    hipMemsetAsync(d_ws, 0, 128, stream);                                   // counts+cursor+offsets
    hipMemsetAsync(d_out, 0, (size_t)T_TOKENS * DIM * sizeof(float), stream); // out accumulator

    router_kernel<<<T_TOKENS / 4, 256, 0, stream>>>(x, gate_w, logits_out, topk_idx, topk_w, counts);
    scan_kernel<<<1, 64, 0, stream>>>(counts, offsets);
    assign_kernel<<<T_TOKENS / 256, 256, 0, stream>>>(topk_idx, topk_w, offsets, cursor, row_token, row_w);
    gather_kernel<<<NPAIRS, 256, 0, stream>>>(x, row_token, xg);

    dim3 g1(32, ISZ / 64, NEXP);   // row tiles x col tiles x experts
    gemm_gu_kernel<<<g1, 256, 0, stream>>>(xg, w_gate, w_up, offsets, counts, h);

    dim3 g2(32, DIM / 64, NEXP);
    gemm_down_kernel<<<g2, 256, 0, stream>>>(h, w_down, offsets, counts, row_token, row_w, out);
}